// Round 3
// baseline (232.967 us; speedup 1.0000x reference)
//
#include <hip/hip_runtime.h>
#include <hip/hip_bf16.h>

#define N_TOKENS   4194304
#define NUM_EXPERTS 8
#define NUM_TASKS   8

// ---------------------------------------------------------------------------
// Kernel 1: fused softmax + label-segmented accumulation.
// One token per lane per grid-stride iteration. Per-thread register
// accumulators acc[8][8] + cnt[8] (all compile-time indexed -> stays in VGPRs,
// ~105 VGPR -> 4 waves/SIMD). End: wave butterfly reduce -> LDS cross-wave
// combine -> 72 global f32 atomics per block (1024 blocks -> trivial
// contention on 72 addresses).
// ---------------------------------------------------------------------------
__global__ __launch_bounds__(256, 4) void mi_reduce_kernel(
    const float* __restrict__ logits,
    const int*   __restrict__ labels,
    float*       __restrict__ ws) {

  float acc[NUM_TASKS][NUM_EXPERTS];
  float cnt[NUM_TASKS];
#pragma unroll
  for (int t = 0; t < NUM_TASKS; ++t) {
    cnt[t] = 0.0f;
#pragma unroll
    for (int e = 0; e < NUM_EXPERTS; ++e) acc[t][e] = 0.0f;
  }

  const int stride = gridDim.x * blockDim.x;
  for (int i = blockIdx.x * blockDim.x + threadIdx.x; i < N_TOKENS; i += stride) {
    const float4* rp = reinterpret_cast<const float4*>(logits + (size_t)i * NUM_EXPERTS);
    float4 v0 = rp[0];
    float4 v1 = rp[1];
    int lab = labels[i];

    float l[8] = {v0.x, v0.y, v0.z, v0.w, v1.x, v1.y, v1.z, v1.w};
    float mx = fmaxf(fmaxf(fmaxf(l[0], l[1]), fmaxf(l[2], l[3])),
                     fmaxf(fmaxf(l[4], l[5]), fmaxf(l[6], l[7])));
    float p[8];
    float S = 0.0f;
#pragma unroll
    for (int e = 0; e < NUM_EXPERTS; ++e) {
      p[e] = __expf(l[e] - mx);
      S += p[e];
    }
    float r = __builtin_amdgcn_rcpf(S);  // ~1 ulp, plenty for 2% tolerance
#pragma unroll
    for (int e = 0; e < NUM_EXPERTS; ++e) p[e] *= r;

    // Predicated segmented accumulation: all indices compile-time constant.
#pragma unroll
    for (int t = 0; t < NUM_TASKS; ++t) {
      float m = (lab == t) ? 1.0f : 0.0f;
      cnt[t] += m;
#pragma unroll
      for (int e = 0; e < NUM_EXPERTS; ++e)
        acc[t][e] = fmaf(m, p[e], acc[t][e]);
    }
  }

  // --- wave butterfly reduce (64 lanes) for all 72 accumulators ---
#pragma unroll
  for (int t = 0; t < NUM_TASKS; ++t) {
#pragma unroll
    for (int e = 0; e < NUM_EXPERTS; ++e) {
      float v = acc[t][e];
#pragma unroll
      for (int m = 1; m < 64; m <<= 1) v += __shfl_xor(v, m, 64);
      acc[t][e] = v;
    }
    float c = cnt[t];
#pragma unroll
    for (int m = 1; m < 64; m <<= 1) c += __shfl_xor(c, m, 64);
    cnt[t] = c;
  }

  // --- cross-wave combine in LDS, then one global atomic per value ---
  __shared__ float sacc[72];
  if (threadIdx.x < 72) sacc[threadIdx.x] = 0.0f;
  __syncthreads();
  if ((threadIdx.x & 63) == 0) {  // lane 0 of each wave holds full wave sums
#pragma unroll
    for (int t = 0; t < NUM_TASKS; ++t) {
#pragma unroll
      for (int e = 0; e < NUM_EXPERTS; ++e)
        atomicAdd(&sacc[t * NUM_EXPERTS + e], acc[t][e]);
      atomicAdd(&sacc[64 + t], cnt[t]);
    }
  }
  __syncthreads();
  if (threadIdx.x < 72) atomicAdd(&ws[threadIdx.x], sacc[threadIdx.x]);
}

// ---------------------------------------------------------------------------
// Kernel 2: single wave computes the mutual-information loss from the
// [8x8] segment sums + [8] counts. Lane i owns entry (t=i/8, e=i%8).
// ---------------------------------------------------------------------------
__global__ void mi_finalize_kernel(const float* __restrict__ ws,
                                   float* __restrict__ out) {
  int lane = threadIdx.x;          // 0..63
  int t = lane >> 3;

  float seg = ws[lane];
  float c   = ws[64 + t];
  float ex  = seg * c;             // EX_gate[t][e]

  // tot = sum(EX_gate) / TOPK
  float s = ex;
#pragma unroll
  for (int m = 1; m < 64; m <<= 1) s += __shfl_xor(s, m, 64);
  float tot = s * 0.5f;            // TOPK = 2
  ex = ex / (tot + 1e-4f);

  // P_TI[t] = row sum over experts (+1e-4): lanes sharing t are xor 1,2,4
  float pti = ex;
  pti += __shfl_xor(pti, 1, 64);
  pti += __shfl_xor(pti, 2, 64);
  pti += __shfl_xor(pti, 4, 64);
  pti += 1e-4f;

  // P_EI[e] = column sum over tasks (+1e-4): lanes sharing e are xor 8,16,32
  float pei = ex;
  pei += __shfl_xor(pei, 8, 64);
  pei += __shfl_xor(pei, 16, 64);
  pei += __shfl_xor(pei, 32, 64);
  pei += 1e-4f;

  float term = -ex * logf(ex / pti / pei + 1e-4f);
#pragma unroll
  for (int m = 1; m < 64; m <<= 1) term += __shfl_xor(term, m, 64);

  if (lane == 0) out[0] = 0.01f * term;   // WEX = 0.01
}

// ---------------------------------------------------------------------------
extern "C" void kernel_launch(void* const* d_in, const int* in_sizes, int n_in,
                              void* d_out, int out_size, void* d_ws, size_t ws_size,
                              hipStream_t stream) {
  const float* logits = (const float*)d_in[0];
  const int*   labels = (const int*)d_in[1];   // jnp.int64 w/o x64 -> int32
  float* out = (float*)d_out;
  float* ws  = (float*)d_ws;

  // ws is re-poisoned to 0xAA before every timed launch; zero the 72
  // accumulators (graph-capturable async memset).
  hipMemsetAsync(ws, 0, 72 * sizeof(float), stream);

  mi_reduce_kernel<<<1024, 256, 0, stream>>>(logits, labels, ws);
  mi_finalize_kernel<<<1, 64, 0, stream>>>(ws, out);
}

// Round 4
// 232.212 us; speedup vs baseline: 1.0033x; 1.0033x over previous
//
#include <hip/hip_runtime.h>
#include <hip/hip_bf16.h>

#define N_TOKENS    4194304
#define NUM_EXPERTS 8
#define NUM_TASKS   8
#define GRID        2048
#define BLOCK       256
#define TOK_PER_THREAD (N_TOKENS / (GRID * BLOCK))   // = 8, exact

// ---------------------------------------------------------------------------
// Kernel 1: fused softmax + label-segmented accumulation.
// One token per lane per iteration, unrolled x4 so the compiler issues
// 8 float4 + 4 label loads back-to-back (latency hiding via ILP, not just
// occupancy — round-3 counters showed latency-bound: 13% HBM, 22% VALU).
// cnt[] removed: counts[t] == sum_e seg_sum[t][e] since softmax rows sum to 1
// (error ~1e-7 rel vs 2% tolerance). acc[8][8] compile-time indexed -> VGPRs.
// ---------------------------------------------------------------------------
__global__ __launch_bounds__(BLOCK) void mi_reduce_kernel(
    const float* __restrict__ logits,
    const int*   __restrict__ labels,
    float*       __restrict__ ws) {

  float acc[NUM_TASKS][NUM_EXPERTS];
#pragma unroll
  for (int t = 0; t < NUM_TASKS; ++t)
#pragma unroll
    for (int e = 0; e < NUM_EXPERTS; ++e) acc[t][e] = 0.0f;

  const int tid = blockIdx.x * BLOCK + threadIdx.x;
  const int S   = GRID * BLOCK;

#pragma unroll 4
  for (int k = 0; k < TOK_PER_THREAD; ++k) {
    const int i = tid + k * S;
    const float4* rp = reinterpret_cast<const float4*>(logits + (size_t)i * NUM_EXPERTS);
    float4 v0 = rp[0];
    float4 v1 = rp[1];
    int lab = labels[i];

    float l[8] = {v0.x, v0.y, v0.z, v0.w, v1.x, v1.y, v1.z, v1.w};
    float mx = fmaxf(fmaxf(fmaxf(l[0], l[1]), fmaxf(l[2], l[3])),
                     fmaxf(fmaxf(l[4], l[5]), fmaxf(l[6], l[7])));
    float p[8];
    float Ssum = 0.0f;
#pragma unroll
    for (int e = 0; e < NUM_EXPERTS; ++e) {
      p[e] = __expf(l[e] - mx);
      Ssum += p[e];
    }
    float r = __builtin_amdgcn_rcpf(Ssum);
#pragma unroll
    for (int e = 0; e < NUM_EXPERTS; ++e) p[e] *= r;

    // Predicated segmented accumulation: all indices compile-time constant.
#pragma unroll
    for (int t = 0; t < NUM_TASKS; ++t) {
      float m = (lab == t) ? 1.0f : 0.0f;
#pragma unroll
      for (int e = 0; e < NUM_EXPERTS; ++e)
        acc[t][e] = fmaf(m, p[e], acc[t][e]);
    }
  }

  // --- wave butterfly reduce (64 lanes) for all 64 accumulators ---
#pragma unroll
  for (int t = 0; t < NUM_TASKS; ++t)
#pragma unroll
    for (int e = 0; e < NUM_EXPERTS; ++e) {
      float v = acc[t][e];
#pragma unroll
      for (int m = 1; m < 64; m <<= 1) v += __shfl_xor(v, m, 64);
      acc[t][e] = v;
    }

  // --- cross-wave combine in LDS, then one global atomic per value ---
  __shared__ float sacc[64];
  if (threadIdx.x < 64) sacc[threadIdx.x] = 0.0f;
  __syncthreads();
  if ((threadIdx.x & 63) == 0) {  // lane 0 of each wave holds full wave sums
#pragma unroll
    for (int t = 0; t < NUM_TASKS; ++t)
#pragma unroll
      for (int e = 0; e < NUM_EXPERTS; ++e)
        atomicAdd(&sacc[t * NUM_EXPERTS + e], acc[t][e]);
  }
  __syncthreads();
  if (threadIdx.x < 64) atomicAdd(&ws[threadIdx.x], sacc[threadIdx.x]);
}

// ---------------------------------------------------------------------------
// Kernel 2: single wave computes the MI loss from the [8x8] segment sums.
// Lane i owns entry (t=i/8, e=i%8). counts[t] recovered as the row sum of
// seg over experts (softmax rows sum to 1).
// ---------------------------------------------------------------------------
__global__ void mi_finalize_kernel(const float* __restrict__ ws,
                                   float* __restrict__ out) {
  int lane = threadIdx.x;          // 0..63

  float seg = ws[lane];

  // counts[t] = row sum over experts: lanes sharing t are xor 1,2,4
  float c = seg;
  c += __shfl_xor(c, 1, 64);
  c += __shfl_xor(c, 2, 64);
  c += __shfl_xor(c, 4, 64);

  float ex = seg * c;              // EX_gate[t][e]

  // tot = sum(EX_gate) / TOPK
  float s = ex;
#pragma unroll
  for (int m = 1; m < 64; m <<= 1) s += __shfl_xor(s, m, 64);
  float tot = s * 0.5f;            // TOPK = 2
  ex = ex / (tot + 1e-4f);

  // P_TI[t] = row sum over experts (+1e-4)
  float pti = ex;
  pti += __shfl_xor(pti, 1, 64);
  pti += __shfl_xor(pti, 2, 64);
  pti += __shfl_xor(pti, 4, 64);
  pti += 1e-4f;

  // P_EI[e] = column sum over tasks (+1e-4)
  float pei = ex;
  pei += __shfl_xor(pei, 8, 64);
  pei += __shfl_xor(pei, 16, 64);
  pei += __shfl_xor(pei, 32, 64);
  pei += 1e-4f;

  float term = -ex * logf(ex / pti / pei + 1e-4f);
#pragma unroll
  for (int m = 1; m < 64; m <<= 1) term += __shfl_xor(term, m, 64);

  if (lane == 0) out[0] = 0.01f * term;   // WEX = 0.01
}

// ---------------------------------------------------------------------------
extern "C" void kernel_launch(void* const* d_in, const int* in_sizes, int n_in,
                              void* d_out, int out_size, void* d_ws, size_t ws_size,
                              hipStream_t stream) {
  const float* logits = (const float*)d_in[0];
  const int*   labels = (const int*)d_in[1];
  float* out = (float*)d_out;
  float* ws  = (float*)d_ws;

  // ws is re-poisoned to 0xAA before every timed launch; zero the 64
  // accumulators (graph-capturable async memset).
  hipMemsetAsync(ws, 0, 64 * sizeof(float), stream);

  mi_reduce_kernel<<<GRID, BLOCK, 0, stream>>>(logits, labels, ws);
  mi_finalize_kernel<<<1, 64, 0, stream>>>(ws, out);
}